// Round 6
// baseline (527.256 us; speedup 1.0000x reference)
//
#include <hip/hip_runtime.h>
#include <hip/hip_bf16.h>

#define B_ 128
#define L_ 1024
#define T_ 512   // L/2 tokens per parity
#define D_ 768
#define CH_ 96   // D/8 chunks of 8 elems
#define DT_ 513  // output tokens per batch
#define TAU_C 1e-3f   // coarse candidate window (~14 sigma of single-bf16 coarse error)

typedef __attribute__((ext_vector_type(8))) short bf16x8;
typedef __attribute__((ext_vector_type(4))) float f32x4;

__device__ __forceinline__ unsigned short f2bf_rne(float x){
    unsigned u = __float_as_uint(x);
    unsigned r = (u + 0x7FFFu + ((u >> 16) & 1u)) >> 16;
    return (unsigned short)r;
}

// ---------------- pack: ALL tokens -> fp64 norm + single bf16, chunk-major per parity ----------------
// packed layout: P[((b*96 + c)*512 + tok)*8 + e], tok = seq>>1, array by seq&1.
__global__ __launch_bounds__(256) void pack_k(const float* __restrict__ hs,
                                              unsigned short* __restrict__ Apk,
                                              unsigned short* __restrict__ Bpk,
                                              double* __restrict__ nsq,
                                              int* __restrict__ paircnt){
    __shared__ __align__(16) unsigned short LhS[CH_ * 16 * 8];  // 24.6 KB
    if (blockIdx.x == 0 && threadIdx.x == 0) *paircnt = 0;
    int b = blockIdx.x >> 6, g = blockIdx.x & 63;   // 16 seq tokens per block
    int wv = threadIdx.x >> 6, lane = threadIdx.x & 63;

    #pragma unroll
    for (int rr = 0; rr < 4; ++rr){
        int jj = wv * 4 + rr;                       // 0..15 within block
        long seq = (long)b * L_ + g * 16 + jj;
        const float4* src = (const float4*)(hs + seq * D_);
        float4 f0 = src[lane], f1 = src[lane + 64], f2 = src[lane + 128];
        double s = 0.0;
        s += (double)f0.x*f0.x + (double)f0.y*f0.y + (double)f0.z*f0.z + (double)f0.w*f0.w;
        s += (double)f1.x*f1.x + (double)f1.y*f1.y + (double)f1.z*f1.z + (double)f1.w*f1.w;
        s += (double)f2.x*f2.x + (double)f2.y*f2.y + (double)f2.z*f2.z + (double)f2.w*f2.w;
        #pragma unroll
        for (int off = 32; off; off >>= 1) s += __shfl_xor(s, off);
        if (lane == 0 && (jj & 1)) nsq[seq] = s;    // odd-token norms for refine
        float rn = (float)(1.0 / sqrt(s));
        float4 fv[3] = {f0, f1, f2};
        #pragma unroll
        for (int t = 0; t < 3; ++t){
            int e0 = t * 256 + lane * 4;
            int c = e0 >> 3, ei = e0 & 7;           // ei = 0 or 4
            float vv[4] = {fv[t].x, fv[t].y, fv[t].z, fv[t].w};
            short4 hv;
            #pragma unroll
            for (int e = 0; e < 4; ++e)
                ((short*)&hv)[e] = (short)f2bf_rne(vv[e] * rn);
            int o = c * 128 + ((jj ^ (c & 7)) << 3) + ei;   // XOR-swizzled (shorts)
            *(short4*)(LhS + o) = hv;
        }
    }
    __syncthreads();
    #pragma unroll
    for (int it = 0; it < 6; ++it){
        int linear = it * 256 + threadIdx.x;
        int c = linear >> 4, jj = linear & 15;
        int o = c * 128 + ((jj ^ (c & 7)) << 3);
        int tok = g * 8 + (jj >> 1);
        long go = ((long)(b * CH_ + c) * T_ + tok) * 8;
        if (jj & 1) *(bf16x8*)(Bpk + go) = *(const bf16x8*)(LhS + o);
        else        *(bf16x8*)(Apk + go) = *(const bf16x8*)(LhS + o);
    }
}

// ---------------- coarse: barrier-free single-pass bf16 MFMA, demand global loads, fused candidates ----------------
// block: 64 A-rows (it 0..7) x ALL 512 B-cols; 4 waves, wave wv owns cols wv*128..+127.
// bid mapping: same-b blocks bid-adjacent (stride 8) on one XCD for packed-slice L2 reuse.
__global__ __launch_bounds__(256, 2) void coarse_k(const unsigned short* __restrict__ Apk,
                                                   const unsigned short* __restrict__ Bpk,
                                                   int* __restrict__ node_idx,
                                                   unsigned long long* __restrict__ rowkey,
                                                   int* __restrict__ paircnt,
                                                   int2* __restrict__ pairs){
    __shared__ float pm1s[64][4];
    __shared__ int   pjs [64][4];
    __shared__ float m1f[64];
    __shared__ int   cnd[64];

    int bid = blockIdx.x;                 // 1024 blocks
    int xcd = bid & 7, q = bid >> 3;
    int it = q & 7, bhi = q >> 3;
    int b = xcd + 8 * bhi;

    int tid = threadIdx.x;
    int wv = tid >> 6, lane = tid & 63, l15 = lane & 15, l4 = lane >> 4;

    long pkbase = (long)b * CH_ * T_;     // in units of 8 shorts
    const unsigned short* pA = Apk + (pkbase + (long)l4 * T_ + it * 64 + l15) * 8;
    const unsigned short* pB = Bpk + (pkbase + (long)l4 * T_ + wv * 128 + l15) * 8;

    f32x4 acc[4][8];
    #pragma unroll
    for (int i = 0; i < 4; ++i)
        #pragma unroll
        for (int j = 0; j < 8; ++j) acc[i][j] = (f32x4){0.f, 0.f, 0.f, 0.f};

    for (int s = 0; s < 24; ++s){
        long ko = (long)s * (4 * T_ * 8);          // advance 4 k-chunks per step
        bf16x8 ah[4];
        #pragma unroll
        for (int ib = 0; ib < 4; ++ib)
            ah[ib] = *(const bf16x8*)(pA + ko + ib * 16 * 8);
        bf16x8 bh[8];
        #pragma unroll
        for (int jb = 0; jb < 8; ++jb)
            bh[jb] = *(const bf16x8*)(pB + ko + jb * 16 * 8);
        #pragma unroll
        for (int jb = 0; jb < 8; ++jb)
            #pragma unroll
            for (int ib = 0; ib < 4; ++ib)
                acc[ib][jb] = __builtin_amdgcn_mfma_f32_16x16x32_bf16(ah[ib], bh[jb], acc[ib][jb], 0, 0, 0);
    }

    // epilogue: per-row max/argmax within wave's 128 cols
    // C layout: row = ib*16 + l4*4 + rr, col = wv*128 + jb*16 + l15
    #pragma unroll
    for (int ib = 0; ib < 4; ++ib)
        #pragma unroll
        for (int rr = 0; rr < 4; ++rr){
            float m1 = -1e30f; int j1 = 0;
            #pragma unroll
            for (int jb = 0; jb < 8; ++jb){   // ascending cols: strict > keeps lowest j
                float v = acc[ib][jb][rr];
                int col = wv * 128 + jb * 16 + l15;
                if (v > m1){ m1 = v; j1 = col; }
            }
            #pragma unroll
            for (int m = 1; m < 16; m <<= 1){
                float o1 = __shfl_xor(m1, m);
                int   oj = __shfl_xor(j1, m);
                if (o1 > m1 || (o1 == m1 && oj < j1)){ m1 = o1; j1 = oj; }
            }
            if (l15 == 0){
                int row = ib * 16 + l4 * 4 + rr;
                pm1s[row][wv] = m1; pjs[row][wv] = j1;
            }
        }
    __syncthreads();
    int grow0 = b * T_ + it * 64;
    if (tid < 64){
        float M1 = -1e30f; int J1 = 0;
        #pragma unroll
        for (int c2 = 0; c2 < 4; ++c2){   // ascending col blocks: ties keep lower j
            float a1 = pm1s[tid][c2]; int aj = pjs[tid][c2];
            if (a1 > M1){ M1 = a1; J1 = aj; }
        }
        node_idx[grow0 + tid] = J1;
        m1f[tid] = M1;
        cnd[tid] = 0;
        rowkey[grow0 + tid] = 0ULL;
    }
    __syncthreads();
    // candidate count per row
    #pragma unroll
    for (int ib = 0; ib < 4; ++ib)
        #pragma unroll
        for (int rr = 0; rr < 4; ++rr){
            int row = ib * 16 + l4 * 4 + rr;
            float thr_ = m1f[row] - TAU_C;
            int hits = 0;
            #pragma unroll
            for (int jb = 0; jb < 8; ++jb) hits += (acc[ib][jb][rr] > thr_) ? 1 : 0;
            if (hits) atomicAdd(&cnd[row], hits);
        }
    __syncthreads();
    // emit refine pairs (includes the argmax itself) for rows with >=2 candidates
    #pragma unroll
    for (int ib = 0; ib < 4; ++ib)
        #pragma unroll
        for (int rr = 0; rr < 4; ++rr){
            int row = ib * 16 + l4 * 4 + rr;
            if (cnd[row] < 2) continue;
            if (it == 0 && row == 0) continue;       // i=0 always unmerged
            float thr_ = m1f[row] - TAU_C;
            #pragma unroll
            for (int jb = 0; jb < 8; ++jb)
                if (acc[ib][jb][rr] > thr_){
                    int p = atomicAdd(paircnt, 1);
                    pairs[p] = make_int2(grow0 + row, wv * 128 + jb * 16 + l15);
                }
        }
}

// ---------------- refine: fp64 exact score for candidate pairs, atomicMax keyed winner ----------------
__global__ __launch_bounds__(256) void refine_k(const float* __restrict__ hs,
                                                const double* __restrict__ nsq,
                                                const int* __restrict__ paircnt,
                                                const int2* __restrict__ pairs,
                                                unsigned long long* __restrict__ rowkey){
    int n = *paircnt;
    int w = threadIdx.x >> 6, lane = threadIdx.x & 63;
    for (int p = blockIdx.x * 4 + w; p < n; p += gridDim.x * 4){
        int2 pr = pairs[p];
        int grow = pr.x, j = pr.y;
        int b = grow >> 9, i = grow & 511;
        const float* ar = hs + ((long)b * L_ + 2 * i) * D_;
        const float* br = hs + ((long)b * L_ + 2 * j + 1) * D_;
        double s = 0.0;
        #pragma unroll
        for (int dd = 0; dd < 12; ++dd){
            int d = dd * 64 + lane;
            s += (double)ar[d] * (double)br[d];
        }
        #pragma unroll
        for (int off = 32; off; off >>= 1) s += __shfl_xor(s, off);
        if (lane == 0){
            double sc = s / sqrt(nsq[(long)b * L_ + 2 * j + 1]);  // row-uniform 1/|a_i| dropped
            unsigned long long bits = (unsigned long long)__double_as_longlong(sc);
            unsigned long long key = (bits >> 63) ? ~bits : (bits | 0x8000000000000000ULL);
            key = (key & ~0xFFFFULL) | (unsigned long long)(511 - j);  // ties -> lowest j
            atomicMax(&rowkey[grow], key);
        }
    }
}

// ---------------- deterministic CSR (stable by source index), rowkey override ----------------
__global__ __launch_bounds__(512) void csr_k(const int* __restrict__ node_idx,
                                             const unsigned long long* __restrict__ rowkey,
                                             int* __restrict__ goff,
                                             int* __restrict__ glist){
    __shared__ int sidx[512];
    __shared__ int off[513];
    __shared__ int tmp[512];
    __shared__ int cnt[512];
    int b = blockIdx.x, t = threadIdx.x;
    unsigned long long rk = rowkey[b * T_ + t];
    sidx[t] = rk ? (511 - (int)(rk & 0xFFFFULL)) : node_idx[b * T_ + t];
    cnt[t] = 0;
    __syncthreads();
    if (t >= 1) atomicAdd(&cnt[sidx[t]], 1);   // i=0 excluded (always unmerged)
    __syncthreads();
    tmp[t] = cnt[t];
    __syncthreads();
    for (int s = 1; s < 512; s <<= 1){
        int v = (t >= s) ? tmp[t - s] : 0;
        __syncthreads();
        tmp[t] += v;
        __syncthreads();
    }
    if (t == 0) off[0] = 0;
    off[t + 1] = tmp[t];
    __syncthreads();
    if (t >= 1){
        int j = sidx[t], r = 0;
        for (int i2 = 1; i2 < t; ++i2) r += (sidx[i2] == j);  // stable rank
        glist[b * T_ + off[j] + r] = t;
    }
    goff[b * 513 + t] = off[t];
    if (t == 0) goff[b * 513 + 512] = off[512];
}

// ---------------- merge: float4 gather-mean per dst token (+mask) ----------------
__global__ __launch_bounds__(192) void merge_k(const float* __restrict__ hs,
                                               const int* __restrict__ goff,
                                               const int* __restrict__ glist,
                                               float* __restrict__ out){
    int bid = blockIdx.x;
    int b = bid / DT_, jj = bid - b * DT_;
    long obase4 = ((long)b * DT_ + jj) * (D_ / 4);
    float4* out4 = (float4*)out;
    if (threadIdx.x == 0) out[(long)B_ * DT_ * D_ + b * DT_ + jj] = 0.0f;  // mask
    int d = threadIdx.x;
    if (jj == 0){  // unmerged token = src[0] = seq 0
        const float4* src = (const float4*)(hs + (long)b * L_ * D_);
        out4[obase4 + d] = src[d];
        return;
    }
    int j = jj - 1;
    int o0 = goff[b * 513 + j], o1 = goff[b * 513 + j + 1];
    const float4* dst = (const float4*)(hs + ((long)b * L_ + 2 * j + 1) * D_);
    float4 a = dst[d];
    for (int s = o0; s < o1; ++s){   // ascending source index: deterministic
        int i = glist[b * T_ + s];
        const float4* srow = (const float4*)(hs + ((long)b * L_ + 2 * i) * D_);
        float4 v = srow[d];
        a.x += v.x; a.y += v.y; a.z += v.z; a.w += v.w;
    }
    float rc = 1.0f / (float)(o1 - o0 + 1);
    a.x *= rc; a.y *= rc; a.z *= rc; a.w *= rc;
    out4[obase4 + d] = a;
}

extern "C" void kernel_launch(void* const* d_in, const int* in_sizes, int n_in,
                              void* d_out, int out_size, void* d_ws, size_t ws_size,
                              hipStream_t stream){
    const float* hs = (const float*)d_in[0];  // (128,1024,768) f32
    float* out = (float*)d_out;
    char* ws = (char*)d_ws;

    const long PSZ = (long)B_ * CH_ * T_ * 8;          // 50,331,648 shorts = 100.66 MB
    unsigned short* Apk = (unsigned short*)ws;
    unsigned short* Bpk = Apk + PSZ;                   // ends at 201,326,592 B
    double* nsq      = (double*)(ws + 201326592);      // 1 MB (odd entries)
    int*    node_idx = (int*)   (ws + 202375168);      // 256 KB
    unsigned long long* rowkey = (unsigned long long*)(ws + 202637312); // 512 KB
    int*    paircnt  = (int*)   (ws + 203161600);      // 256 B
    int*    goff     = (int*)   (ws + 203161856);      // 263168 B
    int*    glist    = (int*)   (ws + 203425024);      // 262144 B
    int2*   pairs    = (int2*)  (ws + 203687168);      // worst-case cap (268 MB), fits ws

    pack_k  <<<B_ * 64, 256, 0, stream>>>(hs, Apk, Bpk, nsq, paircnt);
    coarse_k<<<B_ * 8, 256, 0, stream>>>(Apk, Bpk, node_idx, rowkey, paircnt, pairs);
    refine_k<<<512, 256, 0, stream>>>(hs, nsq, paircnt, pairs, rowkey);
    csr_k   <<<B_, 512, 0, stream>>>(node_idx, rowkey, goff, glist);
    merge_k <<<B_ * DT_, 192, 0, stream>>>(hs, goff, glist, out);
}

// Round 7
// 391.706 us; speedup vs baseline: 1.3460x; 1.3460x over previous
//
#include <hip/hip_runtime.h>
#include <hip/hip_bf16.h>

#define B_ 128
#define L_ 1024
#define T_ 512   // L/2 tokens per parity
#define D_ 768
#define CH_ 96   // D/8 chunks of 8 elems
#define DT_ 513  // output tokens per batch
#define TAU_C 1e-3f   // coarse candidate window (~14 sigma of single-bf16 coarse error)
#define PBUF_ 1024

typedef __attribute__((ext_vector_type(8))) short bf16x8;
typedef __attribute__((ext_vector_type(4))) float f32x4;

typedef const __attribute__((address_space(1))) unsigned int* gas1_t;
typedef __attribute__((address_space(3))) unsigned int* gas3_t;

__device__ __forceinline__ unsigned short f2bf_rne(float x){
    unsigned u = __float_as_uint(x);
    unsigned r = (u + 0x7FFFu + ((u >> 16) & 1u)) >> 16;
    return (unsigned short)r;
}

// ---------------- pack: ALL tokens -> fp64 norm + single bf16, chunk-major per parity ----------------
// packed layout: P[((b*96 + c)*512 + tok)*8 + e], tok = seq>>1, array by seq&1.
__global__ __launch_bounds__(256) void pack_k(const float* __restrict__ hs,
                                              unsigned short* __restrict__ Apk,
                                              unsigned short* __restrict__ Bpk,
                                              double* __restrict__ nsq,
                                              int* __restrict__ paircnt){
    __shared__ __align__(16) unsigned short LhS[CH_ * 16 * 8];  // 24.6 KB
    if (blockIdx.x == 0 && threadIdx.x == 0) *paircnt = 0;
    int b = blockIdx.x >> 6, g = blockIdx.x & 63;   // 16 seq tokens per block
    int wv = threadIdx.x >> 6, lane = threadIdx.x & 63;

    #pragma unroll
    for (int rr = 0; rr < 4; ++rr){
        int jj = wv * 4 + rr;                       // 0..15 within block
        long seq = (long)b * L_ + g * 16 + jj;
        const float4* src = (const float4*)(hs + seq * D_);
        float4 f0 = src[lane], f1 = src[lane + 64], f2 = src[lane + 128];
        double s = 0.0;
        s += (double)f0.x*f0.x + (double)f0.y*f0.y + (double)f0.z*f0.z + (double)f0.w*f0.w;
        s += (double)f1.x*f1.x + (double)f1.y*f1.y + (double)f1.z*f1.z + (double)f1.w*f1.w;
        s += (double)f2.x*f2.x + (double)f2.y*f2.y + (double)f2.z*f2.z + (double)f2.w*f2.w;
        #pragma unroll
        for (int off = 32; off; off >>= 1) s += __shfl_xor(s, off);
        if (lane == 0 && (jj & 1)) nsq[seq] = s;    // odd-token norms for refine
        float rn = (float)(1.0 / sqrt(s));
        float4 fv[3] = {f0, f1, f2};
        #pragma unroll
        for (int t = 0; t < 3; ++t){
            int e0 = t * 256 + lane * 4;
            int c = e0 >> 3, ei = e0 & 7;           // ei = 0 or 4
            float vv[4] = {fv[t].x, fv[t].y, fv[t].z, fv[t].w};
            short4 hv;
            #pragma unroll
            for (int e = 0; e < 4; ++e)
                ((short*)&hv)[e] = (short)f2bf_rne(vv[e] * rn);
            int o = c * 128 + ((jj ^ (c & 7)) << 3) + ei;   // XOR-swizzled (shorts)
            *(short4*)(LhS + o) = hv;
        }
    }
    __syncthreads();
    #pragma unroll
    for (int it = 0; it < 6; ++it){
        int linear = it * 256 + threadIdx.x;
        int c = linear >> 4, jj = linear & 15;
        int o = c * 128 + ((jj ^ (c & 7)) << 3);
        int tok = g * 8 + (jj >> 1);
        long go = ((long)(b * CH_ + c) * T_ + tok) * 8;
        if (jj & 1) *(bf16x8*)(Bpk + go) = *(const bf16x8*)(LhS + o);
        else        *(bf16x8*)(Apk + go) = *(const bf16x8*)(LhS + o);
    }
}

// ---------------- coarse: A tile in LDS (staged once), B reg-dbuf prefetch, fused candidates ----------------
// block: 64 A-rows (it 0..7) x ALL 512 B-cols; 8 waves, wave w owns cols w*64..+63.
// 1 block/CU (96KB LDS); bid mapping keeps same-b blocks on one XCD (B slice L2-resident).
__global__ __launch_bounds__(512, 2) void coarse_k(const unsigned short* __restrict__ Apk,
                                                   const unsigned short* __restrict__ Bpk,
                                                   int* __restrict__ node_idx,
                                                   unsigned long long* __restrict__ rowkey,
                                                   int* __restrict__ paircnt,
                                                   int2* __restrict__ pairs){
    __shared__ __align__(16) unsigned short A_lds[CH_ * 64 * 8];  // 96 KB, [c][row][8]
    __shared__ float pm1s[64][8];
    __shared__ int   pjs [64][8];
    __shared__ float m1f[64];
    __shared__ int   cnd[64];
    __shared__ int2  pbuf[PBUF_];
    __shared__ int   pcnt_s, pbase_s;

    int bid = blockIdx.x;                 // 1024 blocks
    int xcd = bid & 7, q = bid >> 3;
    int it = q & 7, bhi = q >> 3;
    int b = xcd + 8 * bhi;

    int tid = threadIdx.x;
    int w = tid >> 6, lane = tid & 63, l15 = lane & 15, l4 = lane >> 4;

    long pkbase = (long)b * CH_ * T_;     // in units of 8 shorts

    // ---- stage A tile (96 chunks x 64 rows x 16B) via global_load_lds: linear, conflict-free ----
    #pragma unroll
    for (int n = 0; n < 12; ++n){
        int c = w * 12 + n;
        const unsigned short* src = Apk + (pkbase + (long)c * T_ + it * 64 + lane) * 8;
        __builtin_amdgcn_global_load_lds((gas1_t)src, (gas3_t)(A_lds + c * 512), 16, 0, 0);
    }

    const unsigned short* pB0 = Bpk + (pkbase + (long)l4 * T_ + w * 64 + l15) * 8;
    const long KSTEP = (long)4 * T_ * 8;  // shorts per k-step

    f32x4 acc[4][4];
    #pragma unroll
    for (int i = 0; i < 4; ++i)
        #pragma unroll
        for (int j = 0; j < 4; ++j) acc[i][j] = (f32x4){0.f, 0.f, 0.f, 0.f};

    // prologue: B steps 0,1 into regs (fly with A staging)
    bf16x8 bq0[4], bq1[4];
    #pragma unroll
    for (int jb = 0; jb < 4; ++jb){
        bq0[jb] = *(const bf16x8*)(pB0 + 0 * KSTEP + jb * 128);
        bq1[jb] = *(const bf16x8*)(pB0 + 1 * KSTEP + jb * 128);
    }
    __syncthreads();   // A_lds ready (drains vmcnt incl. bq - prologue only)

    if (tid == 0) pcnt_s = 0;

    #pragma unroll
    for (int s = 0; s < 24; ++s){
        bf16x8 bq2[4];
        if (s < 22){                      // issue s+2 loads; fly under MFMA of s, s+1
            #pragma unroll
            for (int jb = 0; jb < 4; ++jb)
                bq2[jb] = *(const bf16x8*)(pB0 + (long)(s + 2) * KSTEP + jb * 128);
        }
        bf16x8 ah[4];
        #pragma unroll
        for (int ib = 0; ib < 4; ++ib)
            ah[ib] = *(const bf16x8*)(A_lds + ((s * 4 + l4) * 64 + ib * 16 + l15) * 8);
        if (s & 1){
            #pragma unroll
            for (int jb = 0; jb < 4; ++jb)
                #pragma unroll
                for (int ib = 0; ib < 4; ++ib)
                    acc[ib][jb] = __builtin_amdgcn_mfma_f32_16x16x32_bf16(ah[ib], bq1[jb], acc[ib][jb], 0, 0, 0);
            if (s < 22){
                #pragma unroll
                for (int jb = 0; jb < 4; ++jb) bq1[jb] = bq2[jb];
            }
        } else {
            #pragma unroll
            for (int jb = 0; jb < 4; ++jb)
                #pragma unroll
                for (int ib = 0; ib < 4; ++ib)
                    acc[ib][jb] = __builtin_amdgcn_mfma_f32_16x16x32_bf16(ah[ib], bq0[jb], acc[ib][jb], 0, 0, 0);
            if (s < 22){
                #pragma unroll
                for (int jb = 0; jb < 4; ++jb) bq0[jb] = bq2[jb];
            }
        }
    }

    // ---- epilogue: per-row max/argmax; C layout: row = ib*16 + l4*4 + rr, col = w*64 + jb*16 + l15 ----
    #pragma unroll
    for (int ib = 0; ib < 4; ++ib)
        #pragma unroll
        for (int rr = 0; rr < 4; ++rr){
            float m1 = -1e30f; int j1 = 0;
            #pragma unroll
            for (int jb = 0; jb < 4; ++jb){   // ascending cols: strict > keeps lowest j
                float v = acc[ib][jb][rr];
                int col = w * 64 + jb * 16 + l15;
                if (v > m1){ m1 = v; j1 = col; }
            }
            #pragma unroll
            for (int m = 1; m < 16; m <<= 1){
                float o1 = __shfl_xor(m1, m);
                int   oj = __shfl_xor(j1, m);
                if (o1 > m1 || (o1 == m1 && oj < j1)){ m1 = o1; j1 = oj; }
            }
            if (l15 == 0){
                int row = ib * 16 + l4 * 4 + rr;
                pm1s[row][w] = m1; pjs[row][w] = j1;
            }
        }
    __syncthreads();
    int grow0 = b * T_ + it * 64;
    if (tid < 64){
        float M1 = -1e30f; int J1 = 0;
        #pragma unroll
        for (int w2 = 0; w2 < 8; ++w2){   // ascending col blocks: ties keep lower j
            float a1 = pm1s[tid][w2]; int aj = pjs[tid][w2];
            if (a1 > M1){ M1 = a1; J1 = aj; }
        }
        node_idx[grow0 + tid] = J1;
        m1f[tid] = M1;
        cnd[tid] = 0;
        rowkey[grow0 + tid] = 0ULL;
    }
    __syncthreads();
    // candidate count per row
    #pragma unroll
    for (int ib = 0; ib < 4; ++ib)
        #pragma unroll
        for (int rr = 0; rr < 4; ++rr){
            int row = ib * 16 + l4 * 4 + rr;
            float thr_ = m1f[row] - TAU_C;
            int hits = 0;
            #pragma unroll
            for (int jb = 0; jb < 4; ++jb) hits += (acc[ib][jb][rr] > thr_) ? 1 : 0;
            if (hits) atomicAdd(&cnd[row], hits);
        }
    __syncthreads();
    // emit refine pairs into LDS (rows with >=2 candidates), then one global reservation
    #pragma unroll
    for (int ib = 0; ib < 4; ++ib)
        #pragma unroll
        for (int rr = 0; rr < 4; ++rr){
            int row = ib * 16 + l4 * 4 + rr;
            if (cnd[row] < 2) continue;
            if (it == 0 && row == 0) continue;       // i=0 always unmerged
            float thr_ = m1f[row] - TAU_C;
            #pragma unroll
            for (int jb = 0; jb < 4; ++jb)
                if (acc[ib][jb][rr] > thr_){
                    int idx = atomicAdd(&pcnt_s, 1);
                    int2 pr = make_int2(grow0 + row, w * 64 + jb * 16 + l15);
                    if (idx < PBUF_) pbuf[idx] = pr;
                    else { int p = atomicAdd(paircnt, 1); pairs[p] = pr; }  // overflow (rare)
                }
        }
    __syncthreads();
    if (tid == 0){
        int n = min(pcnt_s, PBUF_);
        pbase_s = atomicAdd(paircnt, n);
    }
    __syncthreads();
    int n = min(pcnt_s, PBUF_);
    for (int k2 = tid; k2 < n; k2 += 512) pairs[pbase_s + k2] = pbuf[k2];
}

// ---------------- refine: fp64 exact score for candidate pairs, atomicMax keyed winner ----------------
__global__ __launch_bounds__(256) void refine_k(const float* __restrict__ hs,
                                                const double* __restrict__ nsq,
                                                const int* __restrict__ paircnt,
                                                const int2* __restrict__ pairs,
                                                unsigned long long* __restrict__ rowkey){
    int n = *paircnt;
    int w = threadIdx.x >> 6, lane = threadIdx.x & 63;
    for (int p = blockIdx.x * 4 + w; p < n; p += gridDim.x * 4){
        int2 pr = pairs[p];
        int grow = pr.x, j = pr.y;
        int b = grow >> 9, i = grow & 511;
        const float* ar = hs + ((long)b * L_ + 2 * i) * D_;
        const float* br = hs + ((long)b * L_ + 2 * j + 1) * D_;
        double s = 0.0;
        #pragma unroll
        for (int dd = 0; dd < 12; ++dd){
            int d = dd * 64 + lane;
            s += (double)ar[d] * (double)br[d];
        }
        #pragma unroll
        for (int off = 32; off; off >>= 1) s += __shfl_xor(s, off);
        if (lane == 0){
            double sc = s / sqrt(nsq[(long)b * L_ + 2 * j + 1]);  // row-uniform 1/|a_i| dropped
            unsigned long long bits = (unsigned long long)__double_as_longlong(sc);
            unsigned long long key = (bits >> 63) ? ~bits : (bits | 0x8000000000000000ULL);
            key = (key & ~0xFFFFULL) | (unsigned long long)(511 - j);  // ties -> lowest j
            atomicMax(&rowkey[grow], key);
        }
    }
}

// ---------------- deterministic CSR (stable by source index), rowkey override ----------------
__global__ __launch_bounds__(512) void csr_k(const int* __restrict__ node_idx,
                                             const unsigned long long* __restrict__ rowkey,
                                             int* __restrict__ goff,
                                             int* __restrict__ glist){
    __shared__ int sidx[512];
    __shared__ int off[513];
    __shared__ int tmp[512];
    __shared__ int cnt[512];
    int b = blockIdx.x, t = threadIdx.x;
    unsigned long long rk = rowkey[b * T_ + t];
    sidx[t] = rk ? (511 - (int)(rk & 0xFFFFULL)) : node_idx[b * T_ + t];
    cnt[t] = 0;
    __syncthreads();
    if (t >= 1) atomicAdd(&cnt[sidx[t]], 1);   // i=0 excluded (always unmerged)
    __syncthreads();
    tmp[t] = cnt[t];
    __syncthreads();
    for (int s = 1; s < 512; s <<= 1){
        int v = (t >= s) ? tmp[t - s] : 0;
        __syncthreads();
        tmp[t] += v;
        __syncthreads();
    }
    if (t == 0) off[0] = 0;
    off[t + 1] = tmp[t];
    __syncthreads();
    if (t >= 1){
        int j = sidx[t], r = 0;
        for (int i2 = 1; i2 < t; ++i2) r += (sidx[i2] == j);  // stable rank
        glist[b * T_ + off[j] + r] = t;
    }
    goff[b * 513 + t] = off[t];
    if (t == 0) goff[b * 513 + 512] = off[512];
}

// ---------------- merge: float4 gather-mean per dst token (+mask) ----------------
__global__ __launch_bounds__(192) void merge_k(const float* __restrict__ hs,
                                               const int* __restrict__ goff,
                                               const int* __restrict__ glist,
                                               float* __restrict__ out){
    int bid = blockIdx.x;
    int b = bid / DT_, jj = bid - b * DT_;
    long obase4 = ((long)b * DT_ + jj) * (D_ / 4);
    float4* out4 = (float4*)out;
    if (threadIdx.x == 0) out[(long)B_ * DT_ * D_ + b * DT_ + jj] = 0.0f;  // mask
    int d = threadIdx.x;
    if (jj == 0){  // unmerged token = src[0] = seq 0
        const float4* src = (const float4*)(hs + (long)b * L_ * D_);
        out4[obase4 + d] = src[d];
        return;
    }
    int j = jj - 1;
    int o0 = goff[b * 513 + j], o1 = goff[b * 513 + j + 1];
    const float4* dst = (const float4*)(hs + ((long)b * L_ + 2 * j + 1) * D_);
    float4 a = dst[d];
    for (int s = o0; s < o1; ++s){   // ascending source index: deterministic
        int i = glist[b * T_ + s];
        const float4* srow = (const float4*)(hs + ((long)b * L_ + 2 * i) * D_);
        float4 v = srow[d];
        a.x += v.x; a.y += v.y; a.z += v.z; a.w += v.w;
    }
    float rc = 1.0f / (float)(o1 - o0 + 1);
    a.x *= rc; a.y *= rc; a.z *= rc; a.w *= rc;
    out4[obase4 + d] = a;
}

extern "C" void kernel_launch(void* const* d_in, const int* in_sizes, int n_in,
                              void* d_out, int out_size, void* d_ws, size_t ws_size,
                              hipStream_t stream){
    const float* hs = (const float*)d_in[0];  // (128,1024,768) f32
    float* out = (float*)d_out;
    char* ws = (char*)d_ws;

    const long PSZ = (long)B_ * CH_ * T_ * 8;          // 50,331,648 shorts = 100.66 MB
    unsigned short* Apk = (unsigned short*)ws;
    unsigned short* Bpk = Apk + PSZ;                   // ends at 201,326,592 B
    double* nsq      = (double*)(ws + 201326592);      // 1 MB (odd entries)
    int*    node_idx = (int*)   (ws + 202375168);      // 256 KB
    unsigned long long* rowkey = (unsigned long long*)(ws + 202637312); // 512 KB
    int*    paircnt  = (int*)   (ws + 203161600);      // 256 B
    int*    goff     = (int*)   (ws + 203161856);      // 263168 B
    int*    glist    = (int*)   (ws + 203425024);      // 262144 B
    int2*   pairs    = (int2*)  (ws + 203687168);      // large cap, fits ws

    pack_k  <<<B_ * 64, 256, 0, stream>>>(hs, Apk, Bpk, nsq, paircnt);
    coarse_k<<<B_ * 8, 512, 0, stream>>>(Apk, Bpk, node_idx, rowkey, paircnt, pairs);
    refine_k<<<512, 256, 0, stream>>>(hs, nsq, paircnt, pairs, rowkey);
    csr_k   <<<B_, 512, 0, stream>>>(node_idx, rowkey, goff, glist);
    merge_k <<<B_ * DT_, 192, 0, stream>>>(hs, goff, glist, out);
}

// Round 8
// 368.986 us; speedup vs baseline: 1.4289x; 1.0616x over previous
//
#include <hip/hip_runtime.h>
#include <hip/hip_bf16.h>

#define B_ 128
#define L_ 1024
#define T_ 512   // L/2 tokens per parity
#define D_ 768
#define CH_ 96   // D/8 chunks of 8 elems
#define DT_ 513  // output tokens per batch
#define TAU_C 1e-3f   // coarse candidate window (~14 sigma of single-bf16 coarse error)
#define PBUF_ 1024

// LDS geometry (bytes)
#define A_CSTR 1040      // 64 toks * 16B + 16 pad  -> chunk-stride banks +4 (conflict-free)
#define A_BYTES (CH_ * A_CSTR)          // 99840
#define B_CSTR 4112      // 256 toks * 16B + 16 pad
#define B_BUFB (4 * B_CSTR)             // 16448 per half-tile buffer
#define B_OFF A_BYTES                   // B ring starts after A
#define SMEM_BYTES (A_BYTES + 3 * B_BUFB)   // 149184 <= 160K

typedef __attribute__((ext_vector_type(8))) short bf16x8;
typedef __attribute__((ext_vector_type(4))) float f32x4;

typedef const __attribute__((address_space(1))) unsigned int* gas1_t;
typedef __attribute__((address_space(3))) unsigned int* gas3_t;

__device__ __forceinline__ unsigned short f2bf_rne(float x){
    unsigned u = __float_as_uint(x);
    unsigned r = (u + 0x7FFFu + ((u >> 16) & 1u)) >> 16;
    return (unsigned short)r;
}

// ---------------- pack: ALL tokens -> fp64 norm + single bf16, chunk-major per parity ----------------
__global__ __launch_bounds__(256) void pack_k(const float* __restrict__ hs,
                                              unsigned short* __restrict__ Apk,
                                              unsigned short* __restrict__ Bpk,
                                              double* __restrict__ nsq,
                                              int* __restrict__ paircnt){
    __shared__ __align__(16) unsigned short LhS[CH_ * 16 * 8];  // 24.6 KB
    if (blockIdx.x == 0 && threadIdx.x == 0) *paircnt = 0;
    int b = blockIdx.x >> 6, g = blockIdx.x & 63;   // 16 seq tokens per block
    int wv = threadIdx.x >> 6, lane = threadIdx.x & 63;

    #pragma unroll
    for (int rr = 0; rr < 4; ++rr){
        int jj = wv * 4 + rr;                       // 0..15 within block
        long seq = (long)b * L_ + g * 16 + jj;
        const float4* src = (const float4*)(hs + seq * D_);
        float4 f0 = src[lane], f1 = src[lane + 64], f2 = src[lane + 128];
        double s = 0.0;
        s += (double)f0.x*f0.x + (double)f0.y*f0.y + (double)f0.z*f0.z + (double)f0.w*f0.w;
        s += (double)f1.x*f1.x + (double)f1.y*f1.y + (double)f1.z*f1.z + (double)f1.w*f1.w;
        s += (double)f2.x*f2.x + (double)f2.y*f2.y + (double)f2.z*f2.z + (double)f2.w*f2.w;
        #pragma unroll
        for (int off = 32; off; off >>= 1) s += __shfl_xor(s, off);
        if (lane == 0 && (jj & 1)) nsq[seq] = s;    // odd-token norms for refine
        float rn = (float)(1.0 / sqrt(s));
        float4 fv[3] = {f0, f1, f2};
        #pragma unroll
        for (int t = 0; t < 3; ++t){
            int e0 = t * 256 + lane * 4;
            int c = e0 >> 3, ei = e0 & 7;           // ei = 0 or 4
            float vv[4] = {fv[t].x, fv[t].y, fv[t].z, fv[t].w};
            short4 hv;
            #pragma unroll
            for (int e = 0; e < 4; ++e)
                ((short*)&hv)[e] = (short)f2bf_rne(vv[e] * rn);
            int o = c * 128 + ((jj ^ (c & 7)) << 3) + ei;   // XOR-swizzled (shorts)
            *(short4*)(LhS + o) = hv;
        }
    }
    __syncthreads();
    #pragma unroll
    for (int it = 0; it < 6; ++it){
        int linear = it * 256 + threadIdx.x;
        int c = linear >> 4, jj = linear & 15;
        int o = c * 128 + ((jj ^ (c & 7)) << 3);
        int tok = g * 8 + (jj >> 1);
        long go = ((long)(b * CH_ + c) * T_ + tok) * 8;
        if (jj & 1) *(bf16x8*)(Bpk + go) = *(const bf16x8*)(LhS + o);
        else        *(bf16x8*)(Apk + go) = *(const bf16x8*)(LhS + o);
    }
}

// ---------------- coarse: A resident in LDS; B half-tile 3-ring via global_load_lds,
//                  counted vmcnt (T3+T4) + setprio (T5); fused candidates ----------------
// block: 64 A-rows (it 0..7) x 512 B-cols; 8 waves; wave w owns cols {w*32+[0,32)} in EACH half.
__global__ __launch_bounds__(512, 2) void coarse_k(const unsigned short* __restrict__ Apk,
                                                   const unsigned short* __restrict__ Bpk,
                                                   int* __restrict__ node_idx,
                                                   unsigned long long* __restrict__ rowkey,
                                                   int* __restrict__ paircnt,
                                                   int2* __restrict__ pairs){
    __shared__ __align__(16) char SMEM[SMEM_BYTES];

    int bid = blockIdx.x;                 // 1024 blocks
    int xcd = bid & 7, q = bid >> 3;
    int it = q & 7, bhi = q >> 3;
    int b = xcd + 8 * bhi;                // same-b blocks on one XCD (B slice L2-resident)

    int tid = threadIdx.x;
    int w = tid >> 6, lane = tid & 63, l15 = lane & 15, l4 = lane >> 4;

    long pkbase = (long)b * CH_ * T_;     // units of 8 shorts

    // ---- stage A tile: 96 chunk-rows x 1KB, padded stride ----
    #pragma unroll
    for (int n = 0; n < 12; ++n){
        int c = w * 12 + n;
        const unsigned short* src = Apk + (pkbase + (long)c * T_ + it * 64 + lane) * 8;
        __builtin_amdgcn_global_load_lds((gas1_t)src, (gas3_t)(SMEM + c * A_CSTR), 16, 0, 0);
    }
    // ---- stage B phases 0,1 into ring bufs 0,1 ----
    {
        int qq = w, c_rel = qq >> 2, tblk = qq & 3;   // wave does 2 instrs per phase stage
        #pragma unroll
        for (int n = 0; n < 2; ++n){
            int q2 = w + 8 * n, cr = q2 >> 2, tb = q2 & 3;
            // ph0: s=0 h=0
            const unsigned short* s0 = Bpk + (pkbase + (long)cr * T_ + 0 * 256 + tb * 64 + lane) * 8;
            __builtin_amdgcn_global_load_lds((gas1_t)s0, (gas3_t)(SMEM + B_OFF + 0 * B_BUFB + cr * B_CSTR + tb * 1024), 16, 0, 0);
            // ph1: s=0 h=1
            const unsigned short* s1 = Bpk + (pkbase + (long)cr * T_ + 1 * 256 + tb * 64 + lane) * 8;
            __builtin_amdgcn_global_load_lds((gas1_t)s1, (gas3_t)(SMEM + B_OFF + 1 * B_BUFB + cr * B_CSTR + tb * 1024), 16, 0, 0);
        }
        (void)qq; (void)c_rel; (void)tblk;
    }
    __syncthreads();   // vmcnt(0): A + first two B half-tiles resident

    f32x4 acc[4][4];   // [row-group][jb], jb = h*2+g, col = (jb>>1)*256 + w*32 + (jb&1)*16 + l15
    #pragma unroll
    for (int i = 0; i < 4; ++i)
        #pragma unroll
        for (int j = 0; j < 4; ++j) acc[i][j] = (f32x4){0.f, 0.f, 0.f, 0.f};

    bf16x8 ah[4];
    #pragma unroll
    for (int ph = 0; ph < 48; ++ph){
        int s = ph >> 1, h = ph & 1, buf = ph % 3;
        // issue stage for ph+2 (never drained mid-loop: T4)
        if (ph < 46){
            int sn = (ph + 2) >> 1, hn = (ph + 2) & 1, bn = (ph + 2) % 3;
            #pragma unroll
            for (int n = 0; n < 2; ++n){
                int q2 = w + 8 * n, cr = q2 >> 2, tb = q2 & 3;
                const unsigned short* src = Bpk + (pkbase + (long)(sn * 4 + cr) * T_ + hn * 256 + tb * 64 + lane) * 8;
                __builtin_amdgcn_global_load_lds((gas1_t)src, (gas3_t)(SMEM + B_OFF + bn * B_BUFB + cr * B_CSTR + tb * 1024), 16, 0, 0);
            }
        }
        // ds_read fragments (compiler inserts lgkmcnt before MFMA)
        if (h == 0){
            #pragma unroll
            for (int ib = 0; ib < 4; ++ib)
                ah[ib] = *(const bf16x8*)(SMEM + (s * 4 + l4) * A_CSTR + (ib * 16 + l15) * 16);
        }
        bf16x8 bh[2];
        #pragma unroll
        for (int g = 0; g < 2; ++g)
            bh[g] = *(const bf16x8*)(SMEM + B_OFF + buf * B_BUFB + l4 * B_CSTR + (w * 32 + g * 16 + l15) * 16);

        __builtin_amdgcn_s_setprio(1);
        #pragma unroll
        for (int g = 0; g < 2; ++g)
            #pragma unroll
            for (int ib = 0; ib < 4; ++ib)
                acc[ib][h * 2 + g] = __builtin_amdgcn_mfma_f32_16x16x32_bf16(ah[ib], bh[g], acc[ib][h * 2 + g], 0, 0, 0);
        __builtin_amdgcn_s_setprio(0);

        // counted wait: stage(ph+1) must be done; stage(ph+2)'s 2 loads may stay in flight
        if (ph < 46) asm volatile("s_waitcnt vmcnt(2)" ::: "memory");
        else         asm volatile("s_waitcnt vmcnt(0)" ::: "memory");
        __builtin_amdgcn_s_barrier();
        asm volatile("" ::: "memory");
    }

    // ---- epilogue (SMEM overlay; LDS free after final barrier) ----
    float* pm1s = (float*)SMEM;               // [64][8]
    int*   pjs  = (int*)(SMEM + 2048);        // [64][8]
    float* m1f  = (float*)(SMEM + 4096);      // [64]
    int*   cnd  = (int*)(SMEM + 4352);        // [64]
    int2*  pbuf = (int2*)(SMEM + 4608);       // [1024]
    int*   pcnt_s  = (int*)(SMEM + 12800);
    int*   pbase_s = (int*)(SMEM + 12804);

    #pragma unroll
    for (int ib = 0; ib < 4; ++ib)
        #pragma unroll
        for (int rr = 0; rr < 4; ++rr){
            float m1 = -1e30f; int j1 = 0;
            #pragma unroll
            for (int jb2 = 0; jb2 < 4; ++jb2){
                int jb = ((jb2 & 1) << 1) | (jb2 >> 1);   // scan ascending col: h-major
                float v = acc[ib][jb][rr];
                int col = (jb >> 1) * 256 + w * 32 + (jb & 1) * 16 + l15;
                if (v > m1){ m1 = v; j1 = col; }
            }
            #pragma unroll
            for (int m = 1; m < 16; m <<= 1){
                float o1 = __shfl_xor(m1, m);
                int   oj = __shfl_xor(j1, m);
                if (o1 > m1 || (o1 == m1 && oj < j1)){ m1 = o1; j1 = oj; }
            }
            if (l15 == 0){
                int row = ib * 16 + l4 * 4 + rr;
                pm1s[row * 8 + w] = m1; pjs[row * 8 + w] = j1;
            }
        }
    __syncthreads();
    int grow0 = b * T_ + it * 64;
    if (tid < 64){
        float M1 = -1e30f; int J1 = 0;
        #pragma unroll
        for (int w2 = 0; w2 < 8; ++w2){   // any coarse tie across waves -> cnd>=2 -> refine fixes order
            float a1 = pm1s[tid * 8 + w2]; int aj = pjs[tid * 8 + w2];
            if (a1 > M1 || (a1 == M1 && aj < J1)){ M1 = a1; J1 = aj; }
        }
        node_idx[grow0 + tid] = J1;
        m1f[tid] = M1;
        cnd[tid] = 0;
        rowkey[grow0 + tid] = 0ULL;
        if (tid == 0) *pcnt_s = 0;
    }
    __syncthreads();
    #pragma unroll
    for (int ib = 0; ib < 4; ++ib)
        #pragma unroll
        for (int rr = 0; rr < 4; ++rr){
            int row = ib * 16 + l4 * 4 + rr;
            float thr_ = m1f[row] - TAU_C;
            int hits = 0;
            #pragma unroll
            for (int jb = 0; jb < 4; ++jb) hits += (acc[ib][jb][rr] > thr_) ? 1 : 0;
            if (hits) atomicAdd(&cnd[row], hits);
        }
    __syncthreads();
    #pragma unroll
    for (int ib = 0; ib < 4; ++ib)
        #pragma unroll
        for (int rr = 0; rr < 4; ++rr){
            int row = ib * 16 + l4 * 4 + rr;
            if (cnd[row] < 2) continue;
            if (it == 0 && row == 0) continue;       // i=0 always unmerged
            float thr_ = m1f[row] - TAU_C;
            #pragma unroll
            for (int jb = 0; jb < 4; ++jb)
                if (acc[ib][jb][rr] > thr_){
                    int idx = atomicAdd(pcnt_s, 1);
                    int2 pr = make_int2(grow0 + row, (jb >> 1) * 256 + w * 32 + (jb & 1) * 16 + l15);
                    if (idx < PBUF_) pbuf[idx] = pr;
                    else { int p = atomicAdd(paircnt, 1); pairs[p] = pr; }
                }
        }
    __syncthreads();
    if (tid == 0) *pbase_s = atomicAdd(paircnt, min(*pcnt_s, PBUF_));
    __syncthreads();
    int n = min(*pcnt_s, PBUF_);
    for (int k2 = tid; k2 < n; k2 += 512) pairs[*pbase_s + k2] = pbuf[k2];
}

// ---------------- refine: fp64 exact score for candidate pairs, atomicMax keyed winner ----------------
__global__ __launch_bounds__(256) void refine_k(const float* __restrict__ hs,
                                                const double* __restrict__ nsq,
                                                const int* __restrict__ paircnt,
                                                const int2* __restrict__ pairs,
                                                unsigned long long* __restrict__ rowkey){
    int n = *paircnt;
    int w = threadIdx.x >> 6, lane = threadIdx.x & 63;
    for (int p = blockIdx.x * 4 + w; p < n; p += gridDim.x * 4){
        int2 pr = pairs[p];
        int grow = pr.x, j = pr.y;
        int b = grow >> 9, i = grow & 511;
        const float* ar = hs + ((long)b * L_ + 2 * i) * D_;
        const float* br = hs + ((long)b * L_ + 2 * j + 1) * D_;
        double s = 0.0;
        #pragma unroll
        for (int dd = 0; dd < 12; ++dd){
            int d = dd * 64 + lane;
            s += (double)ar[d] * (double)br[d];
        }
        #pragma unroll
        for (int off = 32; off; off >>= 1) s += __shfl_xor(s, off);
        if (lane == 0){
            double sc = s / sqrt(nsq[(long)b * L_ + 2 * j + 1]);  // row-uniform 1/|a_i| dropped
            unsigned long long bits = (unsigned long long)__double_as_longlong(sc);
            unsigned long long key = (bits >> 63) ? ~bits : (bits | 0x8000000000000000ULL);
            key = (key & ~0xFFFFULL) | (unsigned long long)(511 - j);  // ties -> lowest j
            atomicMax(&rowkey[grow], key);
        }
    }
}

// ---------------- deterministic CSR (stable by source index), rowkey override ----------------
__global__ __launch_bounds__(512) void csr_k(const int* __restrict__ node_idx,
                                             const unsigned long long* __restrict__ rowkey,
                                             int* __restrict__ goff,
                                             int* __restrict__ glist){
    __shared__ int sidx[512];
    __shared__ int off[513];
    __shared__ int tmp[512];
    __shared__ int cnt[512];
    int b = blockIdx.x, t = threadIdx.x;
    unsigned long long rk = rowkey[b * T_ + t];
    sidx[t] = rk ? (511 - (int)(rk & 0xFFFFULL)) : node_idx[b * T_ + t];
    cnt[t] = 0;
    __syncthreads();
    if (t >= 1) atomicAdd(&cnt[sidx[t]], 1);   // i=0 excluded (always unmerged)
    __syncthreads();
    tmp[t] = cnt[t];
    __syncthreads();
    for (int s = 1; s < 512; s <<= 1){
        int v = (t >= s) ? tmp[t - s] : 0;
        __syncthreads();
        tmp[t] += v;
        __syncthreads();
    }
    if (t == 0) off[0] = 0;
    off[t + 1] = tmp[t];
    __syncthreads();
    if (t >= 1){
        int j = sidx[t], r = 0;
        for (int i2 = 1; i2 < t; ++i2) r += (sidx[i2] == j);  // stable rank
        glist[b * T_ + off[j] + r] = t;
    }
    goff[b * 513 + t] = off[t];
    if (t == 0) goff[b * 513 + 512] = off[512];
}

// ---------------- merge: float4 gather-mean per dst token (+mask) ----------------
__global__ __launch_bounds__(192) void merge_k(const float* __restrict__ hs,
                                               const int* __restrict__ goff,
                                               const int* __restrict__ glist,
                                               float* __restrict__ out){
    int bid = blockIdx.x;
    int b = bid / DT_, jj = bid - b * DT_;
    long obase4 = ((long)b * DT_ + jj) * (D_ / 4);
    float4* out4 = (float4*)out;
    if (threadIdx.x == 0) out[(long)B_ * DT_ * D_ + b * DT_ + jj] = 0.0f;  // mask
    int d = threadIdx.x;
    if (jj == 0){  // unmerged token = src[0] = seq 0
        const float4* src = (const float4*)(hs + (long)b * L_ * D_);
        out4[obase4 + d] = src[d];
        return;
    }
    int j = jj - 1;
    int o0 = goff[b * 513 + j], o1 = goff[b * 513 + j + 1];
    const float4* dst = (const float4*)(hs + ((long)b * L_ + 2 * j + 1) * D_);
    float4 a = dst[d];
    for (int s = o0; s < o1; ++s){   // ascending source index: deterministic
        int i = glist[b * T_ + s];
        const float4* srow = (const float4*)(hs + ((long)b * L_ + 2 * i) * D_);
        float4 v = srow[d];
        a.x += v.x; a.y += v.y; a.z += v.z; a.w += v.w;
    }
    float rc = 1.0f / (float)(o1 - o0 + 1);
    a.x *= rc; a.y *= rc; a.z *= rc; a.w *= rc;
    out4[obase4 + d] = a;
}

extern "C" void kernel_launch(void* const* d_in, const int* in_sizes, int n_in,
                              void* d_out, int out_size, void* d_ws, size_t ws_size,
                              hipStream_t stream){
    const float* hs = (const float*)d_in[0];  // (128,1024,768) f32
    float* out = (float*)d_out;
    char* ws = (char*)d_ws;

    const long PSZ = (long)B_ * CH_ * T_ * 8;          // 50,331,648 shorts = 100.66 MB
    unsigned short* Apk = (unsigned short*)ws;
    unsigned short* Bpk = Apk + PSZ;                   // ends at 201,326,592 B
    double* nsq      = (double*)(ws + 201326592);      // 1 MB (odd entries)
    int*    node_idx = (int*)   (ws + 202375168);      // 256 KB
    unsigned long long* rowkey = (unsigned long long*)(ws + 202637312); // 512 KB
    int*    paircnt  = (int*)   (ws + 203161600);      // 256 B
    int*    goff     = (int*)   (ws + 203161856);      // 263168 B
    int*    glist    = (int*)   (ws + 203425024);      // 262144 B
    int2*   pairs    = (int2*)  (ws + 203687168);      // large cap, fits ws

    pack_k  <<<B_ * 64, 256, 0, stream>>>(hs, Apk, Bpk, nsq, paircnt);
    coarse_k<<<B_ * 8, 512, 0, stream>>>(Apk, Bpk, node_idx, rowkey, paircnt, pairs);
    refine_k<<<512, 256, 0, stream>>>(hs, nsq, paircnt, pairs, rowkey);
    csr_k   <<<B_, 512, 0, stream>>>(node_idx, rowkey, goff, glist);
    merge_k <<<B_ * DT_, 192, 0, stream>>>(hs, goff, glist, out);
}

// Round 9
// 365.687 us; speedup vs baseline: 1.4418x; 1.0090x over previous
//
#include <hip/hip_runtime.h>
#include <hip/hip_bf16.h>

#define B_ 128
#define L_ 1024
#define T_ 512   // L/2 tokens per parity
#define D_ 768
#define CH_ 96   // D/8 chunks of 8 elems
#define DT_ 513  // output tokens per batch
#define TAU_C 1e-3f   // coarse candidate window (~14 sigma of single-bf16 coarse error)
#define PBUF_ 1024

// coarse LDS ring geometry (bytes): slot = one k-step (4 chunks)
#define KS_B_CSTR 8208                   // 512 toks*16B + 16 pad
#define KS_B_BYTES (4 * KS_B_CSTR)       // 32832
#define KS_A_CSTR 1040                   // 64 toks*16B + 16 pad
#define KS_A_BYTES (4 * KS_A_CSTR)       // 4160
#define KS_BYTES (KS_B_BYTES + KS_A_BYTES)  // 36992
#define SMEM_BYTES (4 * KS_BYTES)        // 147968 <= 160K

typedef __attribute__((ext_vector_type(8))) short bf16x8;
typedef __attribute__((ext_vector_type(4))) float f32x4;

typedef const __attribute__((address_space(1))) unsigned int* gas1_t;
typedef __attribute__((address_space(3))) unsigned int* gas3_t;

__device__ __forceinline__ unsigned short f2bf_rne(float x){
    unsigned u = __float_as_uint(x);
    unsigned r = (u + 0x7FFFu + ((u >> 16) & 1u)) >> 16;
    return (unsigned short)r;
}

// ---------------- pack: ALL tokens -> fp64 norm + single bf16, chunk-major per parity ----------------
__global__ __launch_bounds__(256) void pack_k(const float* __restrict__ hs,
                                              unsigned short* __restrict__ Apk,
                                              unsigned short* __restrict__ Bpk,
                                              double* __restrict__ nsq,
                                              int* __restrict__ paircnt){
    __shared__ __align__(16) unsigned short LhS[CH_ * 16 * 8];  // 24.6 KB
    if (blockIdx.x == 0 && threadIdx.x == 0) *paircnt = 0;
    int b = blockIdx.x >> 6, g = blockIdx.x & 63;   // 16 seq tokens per block
    int wv = threadIdx.x >> 6, lane = threadIdx.x & 63;

    #pragma unroll
    for (int rr = 0; rr < 4; ++rr){
        int jj = wv * 4 + rr;                       // 0..15 within block
        long seq = (long)b * L_ + g * 16 + jj;
        const float4* src = (const float4*)(hs + seq * D_);
        float4 f0 = src[lane], f1 = src[lane + 64], f2 = src[lane + 128];
        double s = 0.0;
        s += (double)f0.x*f0.x + (double)f0.y*f0.y + (double)f0.z*f0.z + (double)f0.w*f0.w;
        s += (double)f1.x*f1.x + (double)f1.y*f1.y + (double)f1.z*f1.z + (double)f1.w*f1.w;
        s += (double)f2.x*f2.x + (double)f2.y*f2.y + (double)f2.z*f2.z + (double)f2.w*f2.w;
        #pragma unroll
        for (int off = 32; off; off >>= 1) s += __shfl_xor(s, off);
        if (lane == 0 && (jj & 1)) nsq[seq] = s;    // odd-token norms for refine
        float rn = (float)(1.0 / sqrt(s));
        float4 fv[3] = {f0, f1, f2};
        #pragma unroll
        for (int t = 0; t < 3; ++t){
            int e0 = t * 256 + lane * 4;
            int c = e0 >> 3, ei = e0 & 7;           // ei = 0 or 4
            float vv[4] = {fv[t].x, fv[t].y, fv[t].z, fv[t].w};
            short4 hv;
            #pragma unroll
            for (int e = 0; e < 4; ++e)
                ((short*)&hv)[e] = (short)f2bf_rne(vv[e] * rn);
            int o = c * 128 + ((jj ^ (c & 7)) << 3) + ei;   // XOR-swizzled (shorts)
            *(short4*)(LhS + o) = hv;
        }
    }
    __syncthreads();
    #pragma unroll
    for (int it = 0; it < 6; ++it){
        int linear = it * 256 + threadIdx.x;
        int c = linear >> 4, jj = linear & 15;
        int o = c * 128 + ((jj ^ (c & 7)) << 3);
        int tok = g * 8 + (jj >> 1);
        long go = ((long)(b * CH_ + c) * T_ + tok) * 8;
        if (jj & 1) *(bf16x8*)(Bpk + go) = *(const bf16x8*)(LhS + o);
        else        *(bf16x8*)(Apk + go) = *(const bf16x8*)(LhS + o);
    }
}

// ---------------- coarse: A+B streamed through 4-slot k-step ring, stage-ahead-3,
//                  counted vmcnt(12), 1 barrier/k-step, 16 MFMA/wave/step ----------------
// block: 64 A-rows (it 0..7) x 512 B-cols; 8 waves; wave w owns cols w*64..+63.
__global__ __launch_bounds__(512, 2) void coarse_k(const unsigned short* __restrict__ Apk,
                                                   const unsigned short* __restrict__ Bpk,
                                                   int* __restrict__ node_idx,
                                                   unsigned long long* __restrict__ rowkey,
                                                   int* __restrict__ paircnt,
                                                   int2* __restrict__ pairs){
    __shared__ __align__(16) char SMEM[SMEM_BYTES];

    int bid = blockIdx.x;                 // 1024 blocks
    int xcd = bid & 7, q = bid >> 3;
    int it = q & 7, bhi = q >> 3;
    int b = xcd + 8 * bhi;                // same-b blocks on one XCD (B slice L2-resident)

    int tid = threadIdx.x;
    int w = tid >> 6, lane = tid & 63, l15 = lane & 15, l4 = lane >> 4;

    long pkbase = (long)b * CH_ * T_;     // units of 8 shorts
    int ca = w >> 1, tb4a = (w & 1) << 1; // A staging: chunk ca, token-blocks tb4a, tb4a+1

    // stage one k-step s into ring slot: 4 B segs (w16) + 2 A segs (w4) per wave
    #define STAGE(s_, slot_) do {                                                          \
        char* dst_ = SMEM + (slot_) * KS_BYTES;                                            \
        _Pragma("unroll")                                                                  \
        for (int n_ = 0; n_ < 4; ++n_){                                                    \
            const unsigned short* sp_ = Bpk + (pkbase + (long)((s_)*4 + n_) * T_ + w * 64 + lane) * 8; \
            __builtin_amdgcn_global_load_lds((gas1_t)sp_, (gas3_t)(dst_ + n_ * KS_B_CSTR + w * 1024), 16, 0, 0); \
        }                                                                                  \
        _Pragma("unroll")                                                                  \
        for (int n_ = 0; n_ < 2; ++n_){                                                    \
            int tb_ = tb4a + n_;                                                           \
            const unsigned short* sp_ = Apk + (pkbase + (long)((s_)*4 + ca) * T_ + it * 64 + tb_ * 16) * 8 + lane * 2; \
            __builtin_amdgcn_global_load_lds((gas1_t)sp_, (gas3_t)(dst_ + KS_B_BYTES + ca * KS_A_CSTR + tb_ * 256), 4, 0, 0); \
        }                                                                                  \
    } while (0)

    // prologue: stage k-steps 0,1,2
    STAGE(0, 0); STAGE(1, 1); STAGE(2, 2);

    f32x4 acc[4][4];   // col = w*64 + jb*16 + l15
    #pragma unroll
    for (int i = 0; i < 4; ++i)
        #pragma unroll
        for (int j = 0; j < 4; ++j) acc[i][j] = (f32x4){0.f, 0.f, 0.f, 0.f};

    __syncthreads();   // drains prologue stages

    #pragma unroll 4
    for (int s = 0; s < 24; ++s){
        if (s < 21) STAGE(s + 3, (s + 3) & 3);
        const char* slot = SMEM + (s & 3) * KS_BYTES;
        bf16x8 ah[4], bh[4];
        #pragma unroll
        for (int ib = 0; ib < 4; ++ib)
            ah[ib] = *(const bf16x8*)(slot + KS_B_BYTES + l4 * KS_A_CSTR + (ib * 16 + l15) * 16);
        #pragma unroll
        for (int jb = 0; jb < 4; ++jb)
            bh[jb] = *(const bf16x8*)(slot + l4 * KS_B_CSTR + (w * 64 + jb * 16 + l15) * 16);
        __builtin_amdgcn_s_setprio(1);
        #pragma unroll
        for (int jb = 0; jb < 4; ++jb)
            #pragma unroll
            for (int ib = 0; ib < 4; ++ib)
                acc[ib][jb] = __builtin_amdgcn_mfma_f32_16x16x32_bf16(ah[ib], bh[jb], acc[ib][jb], 0, 0, 0);
        __builtin_amdgcn_s_setprio(0);
        if (s <= 20)      asm volatile("s_waitcnt vmcnt(12)" ::: "memory");
        else if (s == 21) asm volatile("s_waitcnt vmcnt(6)"  ::: "memory");
        else              asm volatile("s_waitcnt vmcnt(0)"  ::: "memory");
        __builtin_amdgcn_s_barrier();
        asm volatile("" ::: "memory");
    }
    #undef STAGE

    // ---- epilogue (SMEM overlay; ring free after final barrier) ----
    float* pm1s = (float*)SMEM;               // [64][8]
    int*   pjs  = (int*)(SMEM + 2048);        // [64][8]
    float* m1f  = (float*)(SMEM + 4096);      // [64]
    int*   cnd  = (int*)(SMEM + 4352);        // [64]
    int2*  pbuf = (int2*)(SMEM + 4608);       // [1024]
    int*   pcnt_s  = (int*)(SMEM + 12800);
    int*   pbase_s = (int*)(SMEM + 12804);

    #pragma unroll
    for (int ib = 0; ib < 4; ++ib)
        #pragma unroll
        for (int rr = 0; rr < 4; ++rr){
            float m1 = -1e30f; int j1 = 0;
            #pragma unroll
            for (int jb = 0; jb < 4; ++jb){   // ascending cols: strict > keeps lowest j
                float v = acc[ib][jb][rr];
                int col = w * 64 + jb * 16 + l15;
                if (v > m1){ m1 = v; j1 = col; }
            }
            #pragma unroll
            for (int m = 1; m < 16; m <<= 1){
                float o1 = __shfl_xor(m1, m);
                int   oj = __shfl_xor(j1, m);
                if (o1 > m1 || (o1 == m1 && oj < j1)){ m1 = o1; j1 = oj; }
            }
            if (l15 == 0){
                int row = ib * 16 + l4 * 4 + rr;
                pm1s[row * 8 + w] = m1; pjs[row * 8 + w] = j1;
            }
        }
    __syncthreads();
    int grow0 = b * T_ + it * 64;
    if (tid < 64){
        float M1 = -1e30f; int J1 = 0;
        #pragma unroll
        for (int w2 = 0; w2 < 8; ++w2){   // ascending col blocks: ties keep lower j
            float a1 = pm1s[tid * 8 + w2]; int aj = pjs[tid * 8 + w2];
            if (a1 > M1 || (a1 == M1 && aj < J1)){ M1 = a1; J1 = aj; }
        }
        node_idx[grow0 + tid] = J1;
        m1f[tid] = M1;
        cnd[tid] = 0;
        rowkey[grow0 + tid] = 0ULL;
        if (tid == 0) *pcnt_s = 0;
    }
    __syncthreads();
    // candidate count per row (16-lane shfl reduce -> 1 atomic per group)
    #pragma unroll
    for (int ib = 0; ib < 4; ++ib)
        #pragma unroll
        for (int rr = 0; rr < 4; ++rr){
            int row = ib * 16 + l4 * 4 + rr;
            float thr_ = m1f[row] - TAU_C;
            int hits = 0;
            #pragma unroll
            for (int jb = 0; jb < 4; ++jb) hits += (acc[ib][jb][rr] > thr_) ? 1 : 0;
            #pragma unroll
            for (int m = 1; m < 16; m <<= 1) hits += __shfl_xor(hits, m);
            if (l15 == 0 && hits) atomicAdd(&cnd[row], hits);
        }
    __syncthreads();
    #pragma unroll
    for (int ib = 0; ib < 4; ++ib)
        #pragma unroll
        for (int rr = 0; rr < 4; ++rr){
            int row = ib * 16 + l4 * 4 + rr;
            if (cnd[row] < 2) continue;
            if (it == 0 && row == 0) continue;       // i=0 always unmerged
            float thr_ = m1f[row] - TAU_C;
            #pragma unroll
            for (int jb = 0; jb < 4; ++jb)
                if (acc[ib][jb][rr] > thr_){
                    int idx = atomicAdd(pcnt_s, 1);
                    int2 pr = make_int2(grow0 + row, w * 64 + jb * 16 + l15);
                    if (idx < PBUF_) pbuf[idx] = pr;
                    else { int p = atomicAdd(paircnt, 1); pairs[p] = pr; }
                }
        }
    __syncthreads();
    if (tid == 0) *pbase_s = atomicAdd(paircnt, min(*pcnt_s, PBUF_));
    __syncthreads();
    int n = min(*pcnt_s, PBUF_);
    for (int k2 = tid; k2 < n; k2 += 512) pairs[*pbase_s + k2] = pbuf[k2];
}

// ---------------- refine: fp64 exact score for candidate pairs, atomicMax keyed winner ----------------
__global__ __launch_bounds__(256) void refine_k(const float* __restrict__ hs,
                                                const double* __restrict__ nsq,
                                                const int* __restrict__ paircnt,
                                                const int2* __restrict__ pairs,
                                                unsigned long long* __restrict__ rowkey){
    int n = *paircnt;
    int w = threadIdx.x >> 6, lane = threadIdx.x & 63;
    for (int p = blockIdx.x * 4 + w; p < n; p += gridDim.x * 4){
        int2 pr = pairs[p];
        int grow = pr.x, j = pr.y;
        int b = grow >> 9, i = grow & 511;
        const float* ar = hs + ((long)b * L_ + 2 * i) * D_;
        const float* br = hs + ((long)b * L_ + 2 * j + 1) * D_;
        double s = 0.0;
        #pragma unroll
        for (int dd = 0; dd < 12; ++dd){
            int d = dd * 64 + lane;
            s += (double)ar[d] * (double)br[d];
        }
        #pragma unroll
        for (int off = 32; off; off >>= 1) s += __shfl_xor(s, off);
        if (lane == 0){
            double sc = s / sqrt(nsq[(long)b * L_ + 2 * j + 1]);  // row-uniform 1/|a_i| dropped
            unsigned long long bits = (unsigned long long)__double_as_longlong(sc);
            unsigned long long key = (bits >> 63) ? ~bits : (bits | 0x8000000000000000ULL);
            key = (key & ~0xFFFFULL) | (unsigned long long)(511 - j);  // ties -> lowest j
            atomicMax(&rowkey[grow], key);
        }
    }
}

// ---------------- deterministic CSR (stable by source index), rowkey override ----------------
__global__ __launch_bounds__(512) void csr_k(const int* __restrict__ node_idx,
                                             const unsigned long long* __restrict__ rowkey,
                                             int* __restrict__ goff,
                                             int* __restrict__ glist){
    __shared__ int sidx[512];
    __shared__ int off[513];
    __shared__ int tmp[512];
    __shared__ int cnt[512];
    int b = blockIdx.x, t = threadIdx.x;
    unsigned long long rk = rowkey[b * T_ + t];
    sidx[t] = rk ? (511 - (int)(rk & 0xFFFFULL)) : node_idx[b * T_ + t];
    cnt[t] = 0;
    __syncthreads();
    if (t >= 1) atomicAdd(&cnt[sidx[t]], 1);   // i=0 excluded (always unmerged)
    __syncthreads();
    tmp[t] = cnt[t];
    __syncthreads();
    for (int s = 1; s < 512; s <<= 1){
        int v = (t >= s) ? tmp[t - s] : 0;
        __syncthreads();
        tmp[t] += v;
        __syncthreads();
    }
    if (t == 0) off[0] = 0;
    off[t + 1] = tmp[t];
    __syncthreads();
    if (t >= 1){
        int j = sidx[t], r = 0;
        for (int i2 = 1; i2 < t; ++i2) r += (sidx[i2] == j);  // stable rank
        glist[b * T_ + off[j] + r] = t;
    }
    goff[b * 513 + t] = off[t];
    if (t == 0) goff[b * 513 + 512] = off[512];
}

// ---------------- merge: float4 gather-mean per dst token (+mask) ----------------
__global__ __launch_bounds__(192) void merge_k(const float* __restrict__ hs,
                                               const int* __restrict__ goff,
                                               const int* __restrict__ glist,
                                               float* __restrict__ out){
    int bid = blockIdx.x;
    int b = bid / DT_, jj = bid - b * DT_;
    long obase4 = ((long)b * DT_ + jj) * (D_ / 4);
    float4* out4 = (float4*)out;
    if (threadIdx.x == 0) out[(long)B_ * DT_ * D_ + b * DT_ + jj] = 0.0f;  // mask
    int d = threadIdx.x;
    if (jj == 0){  // unmerged token = src[0] = seq 0
        const float4* src = (const float4*)(hs + (long)b * L_ * D_);
        out4[obase4 + d] = src[d];
        return;
    }
    int j = jj - 1;
    int o0 = goff[b * 513 + j], o1 = goff[b * 513 + j + 1];
    const float4* dst = (const float4*)(hs + ((long)b * L_ + 2 * j + 1) * D_);
    float4 a = dst[d];
    for (int s = o0; s < o1; ++s){   // ascending source index: deterministic
        int i = glist[b * T_ + s];
        const float4* srow = (const float4*)(hs + ((long)b * L_ + 2 * i) * D_);
        float4 v = srow[d];
        a.x += v.x; a.y += v.y; a.z += v.z; a.w += v.w;
    }
    float rc = 1.0f / (float)(o1 - o0 + 1);
    a.x *= rc; a.y *= rc; a.z *= rc; a.w *= rc;
    out4[obase4 + d] = a;
}

extern "C" void kernel_launch(void* const* d_in, const int* in_sizes, int n_in,
                              void* d_out, int out_size, void* d_ws, size_t ws_size,
                              hipStream_t stream){
    const float* hs = (const float*)d_in[0];  // (128,1024,768) f32
    float* out = (float*)d_out;
    char* ws = (char*)d_ws;

    const long PSZ = (long)B_ * CH_ * T_ * 8;          // 50,331,648 shorts = 100.66 MB
    unsigned short* Apk = (unsigned short*)ws;
    unsigned short* Bpk = Apk + PSZ;                   // ends at 201,326,592 B
    double* nsq      = (double*)(ws + 201326592);      // 1 MB (odd entries)
    int*    node_idx = (int*)   (ws + 202375168);      // 256 KB
    unsigned long long* rowkey = (unsigned long long*)(ws + 202637312); // 512 KB
    int*    paircnt  = (int*)   (ws + 203161600);      // 256 B
    int*    goff     = (int*)   (ws + 203161856);      // 263168 B
    int*    glist    = (int*)   (ws + 203425024);      // 262144 B
    int2*   pairs    = (int2*)  (ws + 203687168);      // large cap, fits ws

    pack_k  <<<B_ * 64, 256, 0, stream>>>(hs, Apk, Bpk, nsq, paircnt);
    coarse_k<<<B_ * 8, 512, 0, stream>>>(Apk, Bpk, node_idx, rowkey, paircnt, pairs);
    refine_k<<<512, 256, 0, stream>>>(hs, nsq, paircnt, pairs, rowkey);
    csr_k   <<<B_, 512, 0, stream>>>(node_idx, rowkey, goff, glist);
    merge_k <<<B_ * DT_, 192, 0, stream>>>(hs, goff, glist, out);
}

// Round 10
// 328.221 us; speedup vs baseline: 1.6064x; 1.1141x over previous
//
#include <hip/hip_runtime.h>
#include <hip/hip_bf16.h>

#define B_ 128
#define L_ 1024
#define T_ 512   // L/2 tokens per parity
#define D_ 768
#define CH_ 96   // D/8 chunks of 8 elems
#define DT_ 513  // output tokens per batch
#define TAU_C 1e-3f   // coarse candidate window (~14 sigma of single-bf16 coarse error)
#define PBUF_ 1024

// coarse LDS ring: slot = one k-step (4 chunks) of B(512 toks) + A(128 toks)
#define KS_B_CSTR 8208                       // 512*16 + 16 pad
#define KS_B_BYTES (4 * KS_B_CSTR)           // 32832
#define KS_A_CSTR 2064                       // 128*16 + 16 pad
#define KS_A_BYTES (4 * KS_A_CSTR)           // 8256
#define KS_BYTES (KS_B_BYTES + KS_A_BYTES)   // 41088
#define SMEM_BYTES (3 * KS_BYTES)            // 123264 <= 160K

typedef __attribute__((ext_vector_type(8))) short bf16x8;
typedef __attribute__((ext_vector_type(4))) float f32x4;

typedef const __attribute__((address_space(1))) unsigned int* gas1_t;
typedef __attribute__((address_space(3))) unsigned int* gas3_t;

__device__ __forceinline__ unsigned short f2bf_rne(float x){
    unsigned u = __float_as_uint(x);
    unsigned r = (u + 0x7FFFu + ((u >> 16) & 1u)) >> 16;
    return (unsigned short)r;
}

// ---------------- pack: ALL tokens -> fp64 norm + single bf16, chunk-major per parity ----------------
__global__ __launch_bounds__(256) void pack_k(const float* __restrict__ hs,
                                              unsigned short* __restrict__ Apk,
                                              unsigned short* __restrict__ Bpk,
                                              double* __restrict__ nsq,
                                              int* __restrict__ paircnt){
    __shared__ __align__(16) unsigned short LhS[CH_ * 16 * 8];  // 24.6 KB
    if (blockIdx.x == 0 && threadIdx.x == 0) *paircnt = 0;
    int b = blockIdx.x >> 6, g = blockIdx.x & 63;   // 16 seq tokens per block
    int wv = threadIdx.x >> 6, lane = threadIdx.x & 63;

    #pragma unroll
    for (int rr = 0; rr < 4; ++rr){
        int jj = wv * 4 + rr;                       // 0..15 within block
        long seq = (long)b * L_ + g * 16 + jj;
        const float4* src = (const float4*)(hs + seq * D_);
        float4 f0 = src[lane], f1 = src[lane + 64], f2 = src[lane + 128];
        double s = 0.0;
        s += (double)f0.x*f0.x + (double)f0.y*f0.y + (double)f0.z*f0.z + (double)f0.w*f0.w;
        s += (double)f1.x*f1.x + (double)f1.y*f1.y + (double)f1.z*f1.z + (double)f1.w*f1.w;
        s += (double)f2.x*f2.x + (double)f2.y*f2.y + (double)f2.z*f2.z + (double)f2.w*f2.w;
        #pragma unroll
        for (int off = 32; off; off >>= 1) s += __shfl_xor(s, off);
        if (lane == 0 && (jj & 1)) nsq[seq] = s;    // odd-token norms for refine
        float rn = (float)(1.0 / sqrt(s));
        float4 fv[3] = {f0, f1, f2};
        #pragma unroll
        for (int t = 0; t < 3; ++t){
            int e0 = t * 256 + lane * 4;
            int c = e0 >> 3, ei = e0 & 7;           // ei = 0 or 4
            float vv[4] = {fv[t].x, fv[t].y, fv[t].z, fv[t].w};
            short4 hv;
            #pragma unroll
            for (int e = 0; e < 4; ++e)
                ((short*)&hv)[e] = (short)f2bf_rne(vv[e] * rn);
            int o = c * 128 + ((jj ^ (c & 7)) << 3) + ei;   // XOR-swizzled (shorts)
            *(short4*)(LhS + o) = hv;
        }
    }
    __syncthreads();
    #pragma unroll
    for (int it = 0; it < 6; ++it){
        int linear = it * 256 + threadIdx.x;
        int c = linear >> 4, jj = linear & 15;
        int o = c * 128 + ((jj ^ (c & 7)) << 3);
        int tok = g * 8 + (jj >> 1);
        long go = ((long)(b * CH_ + c) * T_ + tok) * 8;
        if (jj & 1) *(bf16x8*)(Bpk + go) = *(const bf16x8*)(LhS + o);
        else        *(bf16x8*)(Apk + go) = *(const bf16x8*)(LhS + o);
    }
}

// ---------------- coarse: 128x512 tile, A+B streamed in 3-slot k-step ring (stage-2-ahead),
//                  counted vmcnt(5), 1 barrier/k-step, 32 MFMA/wave/step ----------------
// 8 waves as 2x4: wave (wr,wc) owns rows wr*64..+63, cols wc*128..+127.
__global__ __launch_bounds__(512, 2) void coarse_k(const unsigned short* __restrict__ Apk,
                                                   const unsigned short* __restrict__ Bpk,
                                                   int* __restrict__ node_idx,
                                                   unsigned long long* __restrict__ rowkey,
                                                   int* __restrict__ paircnt,
                                                   int2* __restrict__ pairs){
    __shared__ __align__(16) char SMEM[SMEM_BYTES];

    int bid = blockIdx.x;                 // 512 blocks
    int xcd = bid & 7, q = bid >> 3;
    int it = q & 3, bhi = q >> 2;
    int b = xcd + 8 * bhi;                // same-b blocks co-scheduled on one XCD

    int tid = threadIdx.x;
    int w = tid >> 6, lane = tid & 63, l15 = lane & 15, l4 = lane >> 4;
    int wr = w >> 2, wc = w & 3;

    long pkbase = (long)b * CH_ * T_;     // units of 8 shorts

    // stage k-step s_ into ring slot: per wave 4 B instrs (one chunk-row each) + 1 A instr
    #define STAGE(s_, slot_) do {                                                          \
        char* dst_ = SMEM + (slot_) * KS_BYTES;                                            \
        _Pragma("unroll")                                                                  \
        for (int n_ = 0; n_ < 4; ++n_){                                                    \
            const unsigned short* sp_ = Bpk + (pkbase + (long)((s_)*4 + n_) * T_ + w * 64 + lane) * 8; \
            __builtin_amdgcn_global_load_lds((gas1_t)sp_, (gas3_t)(dst_ + n_ * KS_B_CSTR + w * 1024), 16, 0, 0); \
        }                                                                                  \
        {                                                                                  \
            const unsigned short* sp_ = Apk + (pkbase + (long)((s_)*4 + (w >> 1)) * T_ + it * 128 + (w & 1) * 64 + lane) * 8; \
            __builtin_amdgcn_global_load_lds((gas1_t)sp_, (gas3_t)(dst_ + KS_B_BYTES + (w >> 1) * KS_A_CSTR + (w & 1) * 1024), 16, 0, 0); \
        }                                                                                  \
    } while (0)

    // prologue: stage k-steps 0,1
    STAGE(0, 0); STAGE(1, 1);

    f32x4 acc[4][8];   // row = wr*64 + ib*16 + l4*4+rr, col = wc*128 + jb*16 + l15
    #pragma unroll
    for (int i = 0; i < 4; ++i)
        #pragma unroll
        for (int j = 0; j < 8; ++j) acc[i][j] = (f32x4){0.f, 0.f, 0.f, 0.f};

    __syncthreads();   // drains prologue stages

    #pragma unroll 3
    for (int s = 0; s < 24; ++s){
        if (s < 22) STAGE(s + 2, (s + 2) % 3);
        const char* slot = SMEM + (s % 3) * KS_BYTES;
        bf16x8 ah[4], bh[8];
        #pragma unroll
        for (int ib = 0; ib < 4; ++ib)
            ah[ib] = *(const bf16x8*)(slot + KS_B_BYTES + l4 * KS_A_CSTR + (wr * 64 + ib * 16 + l15) * 16);
        #pragma unroll
        for (int jb = 0; jb < 8; ++jb)
            bh[jb] = *(const bf16x8*)(slot + l4 * KS_B_CSTR + (wc * 128 + jb * 16 + l15) * 16);
        __builtin_amdgcn_s_setprio(1);
        #pragma unroll
        for (int jb = 0; jb < 8; ++jb)
            #pragma unroll
            for (int ib = 0; ib < 4; ++ib)
                acc[ib][jb] = __builtin_amdgcn_mfma_f32_16x16x32_bf16(ah[ib], bh[jb], acc[ib][jb], 0, 0, 0);
        __builtin_amdgcn_s_setprio(0);
        if (s < 22)      asm volatile("s_waitcnt vmcnt(5)" ::: "memory");
        else             asm volatile("s_waitcnt vmcnt(0)" ::: "memory");
        __builtin_amdgcn_s_barrier();
        asm volatile("" ::: "memory");
    }
    #undef STAGE

    // ---- epilogue (SMEM overlay; ring free after final barrier) ----
    float* pm1s = (float*)SMEM;               // [128][4]
    int*   pjs  = (int*)(SMEM + 2048);        // [128][4]
    float* m1f  = (float*)(SMEM + 4096);      // [128]
    int*   cnd  = (int*)(SMEM + 4608);        // [128]
    int2*  pbuf = (int2*)(SMEM + 5120);       // [1024]
    int*   pcnt_s  = (int*)(SMEM + 13312);
    int*   pbase_s = (int*)(SMEM + 13316);

    #pragma unroll
    for (int ib = 0; ib < 4; ++ib)
        #pragma unroll
        for (int rr = 0; rr < 4; ++rr){
            float m1 = -1e30f; int j1 = 0;
            #pragma unroll
            for (int jb = 0; jb < 8; ++jb){   // ascending cols: strict > keeps lowest j
                float v = acc[ib][jb][rr];
                int col = wc * 128 + jb * 16 + l15;
                if (v > m1){ m1 = v; j1 = col; }
            }
            #pragma unroll
            for (int m = 1; m < 16; m <<= 1){
                float o1 = __shfl_xor(m1, m);
                int   oj = __shfl_xor(j1, m);
                if (o1 > m1 || (o1 == m1 && oj < j1)){ m1 = o1; j1 = oj; }
            }
            if (l15 == 0){
                int row = wr * 64 + ib * 16 + l4 * 4 + rr;
                pm1s[row * 4 + wc] = m1; pjs[row * 4 + wc] = j1;
            }
        }
    __syncthreads();
    int grow0 = b * T_ + it * 128;
    if (tid < 128){
        float M1 = -1e30f; int J1 = 0;
        #pragma unroll
        for (int c2 = 0; c2 < 4; ++c2){   // ascending col blocks: ties keep lower j
            float a1 = pm1s[tid * 4 + c2]; int aj = pjs[tid * 4 + c2];
            if (a1 > M1 || (a1 == M1 && aj < J1)){ M1 = a1; J1 = aj; }
        }
        node_idx[grow0 + tid] = J1;
        m1f[tid] = M1;
        cnd[tid] = 0;
        rowkey[grow0 + tid] = 0ULL;
        if (tid == 0) *pcnt_s = 0;
    }
    __syncthreads();
    // candidate count per row (16-lane shfl reduce -> 1 atomic per group)
    #pragma unroll
    for (int ib = 0; ib < 4; ++ib)
        #pragma unroll
        for (int rr = 0; rr < 4; ++rr){
            int row = wr * 64 + ib * 16 + l4 * 4 + rr;
            float thr_ = m1f[row] - TAU_C;
            int hits = 0;
            #pragma unroll
            for (int jb = 0; jb < 8; ++jb) hits += (acc[ib][jb][rr] > thr_) ? 1 : 0;
            #pragma unroll
            for (int m = 1; m < 16; m <<= 1) hits += __shfl_xor(hits, m);
            if (l15 == 0 && hits) atomicAdd(&cnd[row], hits);
        }
    __syncthreads();
    #pragma unroll
    for (int ib = 0; ib < 4; ++ib)
        #pragma unroll
        for (int rr = 0; rr < 4; ++rr){
            int row = wr * 64 + ib * 16 + l4 * 4 + rr;
            if (cnd[row] < 2) continue;
            if (it == 0 && row == 0) continue;       // i=0 always unmerged
            float thr_ = m1f[row] - TAU_C;
            #pragma unroll
            for (int jb = 0; jb < 8; ++jb)
                if (acc[ib][jb][rr] > thr_){
                    int idx = atomicAdd(pcnt_s, 1);
                    int2 pr = make_int2(grow0 + row, wc * 128 + jb * 16 + l15);
                    if (idx < PBUF_) pbuf[idx] = pr;
                    else { int p = atomicAdd(paircnt, 1); pairs[p] = pr; }
                }
        }
    __syncthreads();
    if (tid == 0) *pbase_s = atomicAdd(paircnt, min(*pcnt_s, PBUF_));
    __syncthreads();
    int n = min(*pcnt_s, PBUF_);
    for (int k2 = tid; k2 < n; k2 += 512) pairs[*pbase_s + k2] = pbuf[k2];
}

// ---------------- refine: fp64 exact score for candidate pairs, atomicMax keyed winner ----------------
__global__ __launch_bounds__(256) void refine_k(const float* __restrict__ hs,
                                                const double* __restrict__ nsq,
                                                const int* __restrict__ paircnt,
                                                const int2* __restrict__ pairs,
                                                unsigned long long* __restrict__ rowkey){
    int n = *paircnt;
    int w = threadIdx.x >> 6, lane = threadIdx.x & 63;
    for (int p = blockIdx.x * 4 + w; p < n; p += gridDim.x * 4){
        int2 pr = pairs[p];
        int grow = pr.x, j = pr.y;
        int b = grow >> 9, i = grow & 511;
        const float* ar = hs + ((long)b * L_ + 2 * i) * D_;
        const float* br = hs + ((long)b * L_ + 2 * j + 1) * D_;
        double s = 0.0;
        #pragma unroll
        for (int dd = 0; dd < 12; ++dd){
            int d = dd * 64 + lane;
            s += (double)ar[d] * (double)br[d];
        }
        #pragma unroll
        for (int off = 32; off; off >>= 1) s += __shfl_xor(s, off);
        if (lane == 0){
            double sc = s / sqrt(nsq[(long)b * L_ + 2 * j + 1]);  // row-uniform 1/|a_i| dropped
            unsigned long long bits = (unsigned long long)__double_as_longlong(sc);
            unsigned long long key = (bits >> 63) ? ~bits : (bits | 0x8000000000000000ULL);
            key = (key & ~0xFFFFULL) | (unsigned long long)(511 - j);  // ties -> lowest j
            atomicMax(&rowkey[grow], key);
        }
    }
}

// ---------------- deterministic CSR (stable by source index), rowkey override ----------------
__global__ __launch_bounds__(512) void csr_k(const int* __restrict__ node_idx,
                                             const unsigned long long* __restrict__ rowkey,
                                             int* __restrict__ goff,
                                             int* __restrict__ glist){
    __shared__ int sidx[512];
    __shared__ int off[513];
    __shared__ int tmp[512];
    __shared__ int cnt[512];
    int b = blockIdx.x, t = threadIdx.x;
    unsigned long long rk = rowkey[b * T_ + t];
    sidx[t] = rk ? (511 - (int)(rk & 0xFFFFULL)) : node_idx[b * T_ + t];
    cnt[t] = 0;
    __syncthreads();
    if (t >= 1) atomicAdd(&cnt[sidx[t]], 1);   // i=0 excluded (always unmerged)
    __syncthreads();
    tmp[t] = cnt[t];
    __syncthreads();
    for (int s = 1; s < 512; s <<= 1){
        int v = (t >= s) ? tmp[t - s] : 0;
        __syncthreads();
        tmp[t] += v;
        __syncthreads();
    }
    if (t == 0) off[0] = 0;
    off[t + 1] = tmp[t];
    __syncthreads();
    if (t >= 1){
        int j = sidx[t], r = 0;
        for (int i2 = 1; i2 < t; ++i2) r += (sidx[i2] == j);  // stable rank
        glist[b * T_ + off[j] + r] = t;
    }
    goff[b * 513 + t] = off[t];
    if (t == 0) goff[b * 513 + 512] = off[512];
}

// ---------------- merge: float4 gather-mean per dst token (+mask) ----------------
__global__ __launch_bounds__(192) void merge_k(const float* __restrict__ hs,
                                               const int* __restrict__ goff,
                                               const int* __restrict__ glist,
                                               float* __restrict__ out){
    int bid = blockIdx.x;
    int b = bid / DT_, jj = bid - b * DT_;
    long obase4 = ((long)b * DT_ + jj) * (D_ / 4);
    float4* out4 = (float4*)out;
    if (threadIdx.x == 0) out[(long)B_ * DT_ * D_ + b * DT_ + jj] = 0.0f;  // mask
    int d = threadIdx.x;
    if (jj == 0){  // unmerged token = src[0] = seq 0
        const float4* src = (const float4*)(hs + (long)b * L_ * D_);
        out4[obase4 + d] = src[d];
        return;
    }
    int j = jj - 1;
    int o0 = goff[b * 513 + j], o1 = goff[b * 513 + j + 1];
    const float4* dst = (const float4*)(hs + ((long)b * L_ + 2 * j + 1) * D_);
    float4 a = dst[d];
    for (int s = o0; s < o1; ++s){   // ascending source index: deterministic
        int i = glist[b * T_ + s];
        const float4* srow = (const float4*)(hs + ((long)b * L_ + 2 * i) * D_);
        float4 v = srow[d];
        a.x += v.x; a.y += v.y; a.z += v.z; a.w += v.w;
    }
    float rc = 1.0f / (float)(o1 - o0 + 1);
    a.x *= rc; a.y *= rc; a.z *= rc; a.w *= rc;
    out4[obase4 + d] = a;
}

extern "C" void kernel_launch(void* const* d_in, const int* in_sizes, int n_in,
                              void* d_out, int out_size, void* d_ws, size_t ws_size,
                              hipStream_t stream){
    const float* hs = (const float*)d_in[0];  // (128,1024,768) f32
    float* out = (float*)d_out;
    char* ws = (char*)d_ws;

    const long PSZ = (long)B_ * CH_ * T_ * 8;          // 50,331,648 shorts = 100.66 MB
    unsigned short* Apk = (unsigned short*)ws;
    unsigned short* Bpk = Apk + PSZ;                   // ends at 201,326,592 B
    double* nsq      = (double*)(ws + 201326592);      // 1 MB (odd entries)
    int*    node_idx = (int*)   (ws + 202375168);      // 256 KB
    unsigned long long* rowkey = (unsigned long long*)(ws + 202637312); // 512 KB
    int*    paircnt  = (int*)   (ws + 203161600);      // 256 B
    int*    goff     = (int*)   (ws + 203161856);      // 263168 B
    int*    glist    = (int*)   (ws + 203425024);      // 262144 B
    int2*   pairs    = (int2*)  (ws + 203687168);      // large cap, fits ws

    pack_k  <<<B_ * 64, 256, 0, stream>>>(hs, Apk, Bpk, nsq, paircnt);
    coarse_k<<<512, 512, 0, stream>>>(Apk, Bpk, node_idx, rowkey, paircnt, pairs);
    refine_k<<<512, 256, 0, stream>>>(hs, nsq, paircnt, pairs, rowkey);
    csr_k   <<<B_, 512, 0, stream>>>(node_idx, rowkey, goff, glist);
    merge_k <<<B_ * DT_, 192, 0, stream>>>(hs, goff, glist, out);
}